// Round 11
// baseline (818.645 us; speedup 1.0000x reference)
//
#include <hip/hip_runtime.h>
#include <hip/hip_bf16.h>

#define N_NODES 100000
#define N_EDGES 1600000
#define IN_DIM_ 256
#define HID_ 256
#define OUT_ 64
#define KSTEPS 10

typedef __attribute__((ext_vector_type(4))) float f32x4;
typedef __attribute__((ext_vector_type(8))) __bf16 bf16x8;
typedef __attribute__((ext_vector_type(8))) unsigned short u16x8;

static __device__ __forceinline__ unsigned short f2bf(float f) {
    union { float f; unsigned int u; } v; v.f = f;
    unsigned int u = v.u;
    unsigned int r = u + 0x7FFFu + ((u >> 16) & 1u);  // RNE
    return (unsigned short)(r >> 16);
}
static __device__ __forceinline__ float bflo(unsigned int v) {
    return __uint_as_float(v << 16);
}
static __device__ __forceinline__ float bfhi(unsigned int v) {
    return __uint_as_float(v & 0xFFFF0000u);
}

// ---------------- small setup kernels ----------------

__global__ void gamma_kernel(const float* __restrict__ alpha, float* __restrict__ gamma) {
    if (threadIdx.x == 0) {
        float m = alpha[0];
        for (int i = 1; i <= KSTEPS; ++i) m = fmaxf(m, alpha[i]);
        float e[KSTEPS + 1];
        float s = 0.f;
        for (int i = 0; i <= KSTEPS; ++i) { e[i] = expf(alpha[i] - m); s += e[i]; }
        float inv = 1.f / s;
        for (int i = 0; i <= KSTEPS; ++i) gamma[i] = e[i] * inv;
    }
}

__global__ void deg_kernel(const int* __restrict__ row, int* __restrict__ deg, int E) {
    int e = blockIdx.x * 256 + threadIdx.x;
    if (e < E) atomicAdd(&deg[row[e]], 1);
}

__global__ void dis_kernel(const int* __restrict__ deg, float* __restrict__ dis, int n) {
    int i = blockIdx.x * 256 + threadIdx.x;
    if (i < n) {
        int d = deg[i];
        dis[i] = d > 0 ? rsqrtf((float)d) : 0.f;
    }
}

// transpose+cast weights once: wT[n][k] = bf16(W[k][n])
__global__ void wcast_kernel(const float* __restrict__ W, unsigned short* __restrict__ wT,
                             int K, int N) {
    int k = blockIdx.x * 256 + threadIdx.x;
    int n = blockIdx.y;
    if (k < K) wT[(size_t)n * K + k] = f2bf(W[(size_t)k * N + n]);
}

// ---------------- hierarchical scan ----------------

__global__ __launch_bounds__(256) void scan_sum_kernel(const int* __restrict__ deg,
                                                       int* __restrict__ bsum, int n) {
    __shared__ int s[256];
    int t = threadIdx.x;
    int i = blockIdx.x * 256 + t;
    s[t] = (i < n) ? deg[i] : 0;
    __syncthreads();
    for (int st = 128; st > 0; st >>= 1) {
        if (t < st) s[t] += s[t + st];
        __syncthreads();
    }
    if (t == 0) bsum[blockIdx.x] = s[0];
}

__global__ __launch_bounds__(512) void scan_block_kernel(int* __restrict__ bsum,
                                                         int* __restrict__ off,
                                                         int nblk, int n) {
    __shared__ int s[512];
    int t = threadIdx.x;
    int v = (t < nblk) ? bsum[t] : 0;
    s[t] = v;
    __syncthreads();
    for (int st = 1; st < 512; st <<= 1) {
        int a = (t >= st) ? s[t - st] : 0;
        __syncthreads();
        s[t] += a;
        __syncthreads();
    }
    if (t < nblk) bsum[t] = s[t] - v;  // exclusive
    if (t == 511) off[n] = s[511];     // total = E
}

__global__ __launch_bounds__(256) void scan_final_kernel(const int* __restrict__ deg,
                                                         const int* __restrict__ bsum,
                                                         int* __restrict__ off, int n) {
    __shared__ int s[256];
    int t = threadIdx.x;
    int i = blockIdx.x * 256 + t;
    int v = (i < n) ? deg[i] : 0;
    s[t] = v;
    __syncthreads();
    for (int st = 1; st < 256; st <<= 1) {
        int a = (t >= st) ? s[t - st] : 0;
        __syncthreads();
        s[t] += a;
        __syncthreads();
    }
    if (i < n) off[i] = bsum[blockIdx.x] + s[t] - v;
}

// R11: direct scatter swept by COL range. Each sweep appends only edges whose
// source (col) lies in a 12.5K-node window (1.6MB of hc) -> every row's list is
// segmented into ascending col-windows. During pull, all waves walk window 0,
// then 1, ... in loose lockstep -> instantaneous gather working set ~1.6MB,
// fits per-XCD L2 (4MB). One-time cost: re-read row/col 8x (~+50us, R9-measured).
__global__ void csr_scatter_kernel(const int* __restrict__ row, const int* __restrict__ col,
                                   const float* __restrict__ dis, const int* __restrict__ off,
                                   int* __restrict__ cursor, int2* __restrict__ ecsr, int E,
                                   int clo, int chi) {
    int e = blockIdx.x * 256 + threadIdx.x;
    if (e < E) {
        int c = col[e];
        if (c >= clo && c < chi) {
            int r = row[e];
            float w = dis[r] * dis[c];
            int pos = atomicAdd(&cursor[r], 1);
            int2 p;
            p.x = c;
            p.y = __float_as_int(w);
            ecsr[(size_t)off[r] + pos] = p;
        }
    }
}

// ---------------- MLP ----------------
// GEMM1 single-pass: block computes 64 rows x 256 cols. x fetched exactly once.
__global__ __launch_bounds__(256) void gemm1_kernel(const float* __restrict__ x,
                                                    const unsigned short* __restrict__ w1T,
                                                    const float* __restrict__ b1,
                                                    unsigned short* __restrict__ h1, int M) {
    __shared__ unsigned short As[64][40];
    __shared__ unsigned short Bs[256][40];

    const int tid = threadIdx.x;
    const int lane = tid & 63;
    const int w = tid >> 6;
    const int wr = w >> 1, wc = w & 1;          // wave tile: rows wr*32, cols wc*128
    const int row0 = blockIdx.x * 64;

    const int am = tid >> 2;
    const int ak = (tid & 3) * 8;

    f32x4 acc[2][8] = {};

    for (int kk = 0; kk < 256; kk += 32) {
        {
            int gr = row0 + am;
            u16x8 av;
            if (gr < M) {
                const float* p = x + (size_t)gr * IN_DIM_ + kk + ak;
                #pragma unroll
                for (int j = 0; j < 8; ++j) av[j] = f2bf(p[j]);
            } else {
                #pragma unroll
                for (int j = 0; j < 8; ++j) av[j] = 0;
            }
            *(u16x8*)&As[am][ak] = av;
        }
        {
            const unsigned short* p = w1T + (size_t)tid * 256 + kk;
            *(u16x8*)&Bs[tid][0]  = *(const u16x8*)&p[0];
            *(u16x8*)&Bs[tid][8]  = *(const u16x8*)&p[8];
            *(u16x8*)&Bs[tid][16] = *(const u16x8*)&p[16];
            *(u16x8*)&Bs[tid][24] = *(const u16x8*)&p[24];
        }
        __syncthreads();

        const int fr = lane & 15;
        const int ko = (lane >> 4) * 8;
        bf16x8 a[2];
        #pragma unroll
        for (int mi = 0; mi < 2; ++mi) a[mi] = *(const bf16x8*)&As[wr * 32 + mi * 16 + fr][ko];
        #pragma unroll
        for (int ni = 0; ni < 8; ++ni) {
            bf16x8 b = *(const bf16x8*)&Bs[wc * 128 + ni * 16 + fr][ko];
            #pragma unroll
            for (int mi = 0; mi < 2; ++mi)
                acc[mi][ni] = __builtin_amdgcn_mfma_f32_16x16x32_bf16(a[mi], b, acc[mi][ni], 0, 0, 0);
        }
        __syncthreads();
    }

    const int fr = lane & 15;
    const int rg = (lane >> 4) * 4;
    #pragma unroll
    for (int mi = 0; mi < 2; ++mi) {
        #pragma unroll
        for (int r = 0; r < 4; ++r) {
            int gm = row0 + wr * 32 + mi * 16 + rg + r;
            if (gm < M) {
                #pragma unroll
                for (int ni = 0; ni < 8; ++ni) {
                    int gn = wc * 128 + ni * 16 + fr;
                    float v = acc[mi][ni][r] + b1[gn];
                    v = fmaxf(v, 0.f);
                    h1[(size_t)gm * HID_ + gn] = f2bf(v);
                }
            }
        }
    }
}

// GEMM2: h = h1 @ W2 + b2 -> h bf16 [M,64]; out = gamma0*h (f32 pre-rounding)
__global__ __launch_bounds__(256) void gemm2_kernel(const unsigned short* __restrict__ h1,
                                                    const unsigned short* __restrict__ w2T,
                                                    const float* __restrict__ b2,
                                                    const float* __restrict__ gamma,
                                                    unsigned short* __restrict__ h,
                                                    float* __restrict__ out, int M) {
    __shared__ unsigned short As[64][40];
    __shared__ unsigned short Bs[64][40];

    const int tid = threadIdx.x;
    const int lane = tid & 63;
    const int w = tid >> 6;
    const int wr = w >> 1, wc = w & 1;
    const int row0 = blockIdx.x * 64;

    const int am = tid >> 2;
    const int ak = (tid & 3) * 8;

    f32x4 acc[2][2] = {};

    for (int kk = 0; kk < 256; kk += 32) {
        {
            int gr = row0 + am;
            if (gr < M) {
                *(u16x8*)&As[am][ak] = *(const u16x8*)&h1[(size_t)gr * HID_ + kk + ak];
            } else {
                u16x8 z = {};
                *(u16x8*)&As[am][ak] = z;
            }
        }
        if (tid < 128) {
            int n = tid >> 1, hf = (tid & 1) * 16;
            const unsigned short* p = &w2T[(size_t)n * 256 + kk + hf];
            *(u16x8*)&Bs[n][hf]     = *(const u16x8*)&p[0];
            *(u16x8*)&Bs[n][hf + 8] = *(const u16x8*)&p[8];
        }
        __syncthreads();

        const int fr = lane & 15;
        const int ko = (lane >> 4) * 8;
        bf16x8 a[2], b[2];
        #pragma unroll
        for (int mi = 0; mi < 2; ++mi) a[mi] = *(const bf16x8*)&As[wr * 32 + mi * 16 + fr][ko];
        #pragma unroll
        for (int ni = 0; ni < 2; ++ni) b[ni] = *(const bf16x8*)&Bs[wc * 32 + ni * 16 + fr][ko];
        #pragma unroll
        for (int mi = 0; mi < 2; ++mi)
            #pragma unroll
            for (int ni = 0; ni < 2; ++ni)
                acc[mi][ni] = __builtin_amdgcn_mfma_f32_16x16x32_bf16(a[mi], b[ni], acc[mi][ni], 0, 0, 0);
        __syncthreads();
    }

    const float g0 = gamma[0];
    const int fr = lane & 15;
    const int rg = (lane >> 4) * 4;
    #pragma unroll
    for (int mi = 0; mi < 2; ++mi) {
        #pragma unroll
        for (int r = 0; r < 4; ++r) {
            int gm = row0 + wr * 32 + mi * 16 + rg + r;
            if (gm < M) {
                #pragma unroll
                for (int ni = 0; ni < 2; ++ni) {
                    int gn = wc * 32 + ni * 16 + fr;
                    float v = acc[mi][ni][r] + b2[gn];
                    h[(size_t)gm * OUT_ + gn] = f2bf(v);
                    out[(size_t)gm * OUT_ + gn] = g0 * v;
                }
            }
        }
    }
}

// ---------------- propagation: R6 pull + window-2 fusion; last hn store skipped ----------------
__global__ __launch_bounds__(256) void pull_kernel(const int* __restrict__ off,
                                                   const int2* __restrict__ ecsr,
                                                   const unsigned short* __restrict__ hc,
                                                   unsigned short* __restrict__ hn,
                                                   float* __restrict__ out,
                                                   const float* __restrict__ gamma,
                                                   int k, int fuse, int n) {
    int node = blockIdx.x * 4 + (threadIdx.x >> 6);
    if (node >= n) return;
    int lane = threadIdx.x & 63;
    int half = lane >> 5;
    int fl = (lane & 31) * 2;
    int s = off[node], e = off[node + 1];
    float acc0 = 0.f, acc1 = 0.f;

    int j = s + half;
    // 8 edges per half per iteration -> 8 outstanding gathers per lane
    for (; j + 14 < e; j += 16) {
        int2 p0 = ecsr[j],      p1 = ecsr[j + 2],  p2 = ecsr[j + 4],  p3 = ecsr[j + 6];
        int2 p4 = ecsr[j + 8],  p5 = ecsr[j + 10], p6 = ecsr[j + 12], p7 = ecsr[j + 14];
        unsigned int v0 = *(const unsigned int*)&hc[(size_t)p0.x * OUT_ + fl];
        unsigned int v1 = *(const unsigned int*)&hc[(size_t)p1.x * OUT_ + fl];
        unsigned int v2 = *(const unsigned int*)&hc[(size_t)p2.x * OUT_ + fl];
        unsigned int v3 = *(const unsigned int*)&hc[(size_t)p3.x * OUT_ + fl];
        unsigned int v4 = *(const unsigned int*)&hc[(size_t)p4.x * OUT_ + fl];
        unsigned int v5 = *(const unsigned int*)&hc[(size_t)p5.x * OUT_ + fl];
        unsigned int v6 = *(const unsigned int*)&hc[(size_t)p6.x * OUT_ + fl];
        unsigned int v7 = *(const unsigned int*)&hc[(size_t)p7.x * OUT_ + fl];
        float w0 = __int_as_float(p0.y), w1 = __int_as_float(p1.y);
        float w2 = __int_as_float(p2.y), w3 = __int_as_float(p3.y);
        float w4 = __int_as_float(p4.y), w5 = __int_as_float(p5.y);
        float w6 = __int_as_float(p6.y), w7 = __int_as_float(p7.y);
        acc0 += w0 * bflo(v0); acc1 += w0 * bfhi(v0);
        acc0 += w1 * bflo(v1); acc1 += w1 * bfhi(v1);
        acc0 += w2 * bflo(v2); acc1 += w2 * bfhi(v2);
        acc0 += w3 * bflo(v3); acc1 += w3 * bfhi(v3);
        acc0 += w4 * bflo(v4); acc1 += w4 * bfhi(v4);
        acc0 += w5 * bflo(v5); acc1 += w5 * bfhi(v5);
        acc0 += w6 * bflo(v6); acc1 += w6 * bfhi(v6);
        acc0 += w7 * bflo(v7); acc1 += w7 * bfhi(v7);
    }
    for (; j + 2 < e; j += 4) {
        int2 pa = ecsr[j], pb = ecsr[j + 2];
        unsigned int va = *(const unsigned int*)&hc[(size_t)pa.x * OUT_ + fl];
        unsigned int vb = *(const unsigned int*)&hc[(size_t)pb.x * OUT_ + fl];
        float wa = __int_as_float(pa.y), wb = __int_as_float(pb.y);
        acc0 += wa * bflo(va); acc1 += wa * bfhi(va);
        acc0 += wb * bflo(vb); acc1 += wb * bfhi(vb);
    }
    if (j < e) {
        int2 p = ecsr[j];
        unsigned int v = *(const unsigned int*)&hc[(size_t)p.x * OUT_ + fl];
        float w = __int_as_float(p.y);
        acc0 += w * bflo(v);
        acc1 += w * bfhi(v);
    }

    acc0 += __shfl_xor(acc0, 32);
    acc1 += __shfl_xor(acc1, 32);

    if (lane < 32) {
        size_t o = (size_t)node * OUT_ + fl;
        if (k < KSTEPS) {  // h_K itself is never re-read; only its gamma-term matters
            unsigned int packed = (unsigned int)f2bf(acc0) | ((unsigned int)f2bf(acc1) << 16);
            *(unsigned int*)&hn[o] = packed;
        }
        if (fuse) {
            float gp = gamma[k - 1], gc = gamma[k];
            unsigned int hown = *(const unsigned int*)&hc[o];  // own row h_{k-1}[node]
            float2* op = (float2*)&out[o];
            float2 ov = *op;
            ov.x += gp * bflo(hown) + gc * acc0;
            ov.y += gp * bfhi(hown) + gc * acc1;
            *op = ov;
        }
    }
}

// ---------------- launcher ----------------
extern "C" void kernel_launch(void* const* d_in, const int* in_sizes, int n_in,
                              void* d_out, int out_size, void* d_ws, size_t ws_size,
                              hipStream_t stream) {
    const float* x = (const float*)d_in[0];
    const int* ei = (const int*)d_in[1];
    const float* W1 = (const float*)d_in[2];
    const float* b1 = (const float*)d_in[3];
    const float* W2 = (const float*)d_in[4];
    const float* b2 = (const float*)d_in[5];
    const float* alpha = (const float*)d_in[6];
    const int* row = ei;
    const int* col = ei + N_EDGES;
    float* out = (float*)d_out;

    const int NBLK = (N_NODES + 255) / 256;   // 391

    char* wsb = (char*)d_ws;
    size_t p = 0;
    auto alloc = [&](size_t bytes) { size_t r = p; p += (bytes + 255) & ~255ull; return r; };
    float* gamma = (float*)(wsb + alloc(16 * 4));
    int* off     = (int*)(wsb + alloc((N_NODES + 1) * 4));
    int* cursor  = (int*)(wsb + alloc(N_NODES * 4));
    int* deg     = (int*)(wsb + alloc(N_NODES * 4));
    float* dis   = (float*)(wsb + alloc(N_NODES * 4));
    int* bsum    = (int*)(wsb + alloc(512 * 4));
    unsigned short* w1T = (unsigned short*)(wsb + alloc((size_t)IN_DIM_ * HID_ * 2));
    unsigned short* w2T = (unsigned short*)(wsb + alloc((size_t)HID_ * OUT_ * 2));
    int2* ecsr   = (int2*)(wsb + alloc((size_t)N_EDGES * 8));
    unsigned short* h1  = (unsigned short*)(wsb + alloc((size_t)N_NODES * HID_ * 2)); // 51.2MB
    unsigned short* h_a = (unsigned short*)(wsb + alloc((size_t)N_NODES * OUT_ * 2)); // 12.8MB
    unsigned short* h_b = h1;  // h1 dead after gemm2

    hipMemsetAsync(cursor, 0, N_NODES * sizeof(int), stream);
    hipMemsetAsync(deg, 0, N_NODES * sizeof(int), stream);
    gamma_kernel<<<1, 64, 0, stream>>>(alpha, gamma);
    deg_kernel<<<(N_EDGES + 255) / 256, 256, 0, stream>>>(row, deg, N_EDGES);
    dis_kernel<<<NBLK, 256, 0, stream>>>(deg, dis, N_NODES);
    scan_sum_kernel<<<NBLK, 256, 0, stream>>>(deg, bsum, N_NODES);
    scan_block_kernel<<<1, 512, 0, stream>>>(bsum, off, NBLK, N_NODES);
    scan_final_kernel<<<NBLK, 256, 0, stream>>>(deg, bsum, off, N_NODES);
    for (int s = 0; s < 8; ++s) {  // col-window sweeps: approximate col-sort per row
        csr_scatter_kernel<<<(N_EDGES + 255) / 256, 256, 0, stream>>>(
            row, col, dis, off, cursor, ecsr, N_EDGES, s * 12500, (s + 1) * 12500);
    }
    wcast_kernel<<<dim3(1, HID_), 256, 0, stream>>>(W1, w1T, IN_DIM_, HID_);
    wcast_kernel<<<dim3(1, OUT_), 256, 0, stream>>>(W2, w2T, HID_, OUT_);

    gemm1_kernel<<<(N_NODES + 63) / 64, 256, 0, stream>>>(x, w1T, b1, h1, N_NODES);
    gemm2_kernel<<<(N_NODES + 63) / 64, 256, 0, stream>>>(h1, w2T, b2, gamma, h_a, out, N_NODES);

    unsigned short* hc = h_a;
    unsigned short* hn = h_b;
    for (int k = 1; k <= KSTEPS; ++k) {
        int fuse = (k % 2 == 0);  // even steps fold gamma_{k-1} and gamma_k into out
        pull_kernel<<<(N_NODES + 3) / 4, 256, 0, stream>>>(off, ecsr, hc, hn, out, gamma, k,
                                                           fuse, N_NODES);
        unsigned short* t = hc; hc = hn; hn = t;
    }
}

// Round 12
// 807.170 us; speedup vs baseline: 1.0142x; 1.0142x over previous
//
#include <hip/hip_runtime.h>
#include <hip/hip_bf16.h>

#define N_NODES 100000
#define N_EDGES 1600000
#define IN_DIM_ 256
#define HID_ 256
#define OUT_ 64
#define KSTEPS 10

typedef __attribute__((ext_vector_type(4))) float f32x4;
typedef __attribute__((ext_vector_type(8))) __bf16 bf16x8;
typedef __attribute__((ext_vector_type(8))) unsigned short u16x8;

static __device__ __forceinline__ unsigned short f2bf(float f) {
    union { float f; unsigned int u; } v; v.f = f;
    unsigned int u = v.u;
    unsigned int r = u + 0x7FFFu + ((u >> 16) & 1u);  // RNE
    return (unsigned short)(r >> 16);
}
static __device__ __forceinline__ float bflo(unsigned int v) {
    return __uint_as_float(v << 16);
}
static __device__ __forceinline__ float bfhi(unsigned int v) {
    return __uint_as_float(v & 0xFFFF0000u);
}

// ---------------- small setup kernels ----------------

__global__ void gamma_kernel(const float* __restrict__ alpha, float* __restrict__ gamma) {
    if (threadIdx.x == 0) {
        float m = alpha[0];
        for (int i = 1; i <= KSTEPS; ++i) m = fmaxf(m, alpha[i]);
        float e[KSTEPS + 1];
        float s = 0.f;
        for (int i = 0; i <= KSTEPS; ++i) { e[i] = expf(alpha[i] - m); s += e[i]; }
        float inv = 1.f / s;
        for (int i = 0; i <= KSTEPS; ++i) gamma[i] = e[i] * inv;
    }
}

__global__ void deg_kernel(const int* __restrict__ row, int* __restrict__ deg, int E) {
    int e = blockIdx.x * 256 + threadIdx.x;
    if (e < E) atomicAdd(&deg[row[e]], 1);
}

__global__ void dis_kernel(const int* __restrict__ deg, float* __restrict__ dis, int n) {
    int i = blockIdx.x * 256 + threadIdx.x;
    if (i < n) {
        int d = deg[i];
        dis[i] = d > 0 ? rsqrtf((float)d) : 0.f;
    }
}

// transpose+cast weights once: wT[n][k] = bf16(W[k][n])
__global__ void wcast_kernel(const float* __restrict__ W, unsigned short* __restrict__ wT,
                             int K, int N) {
    int k = blockIdx.x * 256 + threadIdx.x;
    int n = blockIdx.y;
    if (k < K) wT[(size_t)n * K + k] = f2bf(W[(size_t)k * N + n]);
}

// ---------------- hierarchical scan ----------------

__global__ __launch_bounds__(256) void scan_sum_kernel(const int* __restrict__ deg,
                                                       int* __restrict__ bsum, int n) {
    __shared__ int s[256];
    int t = threadIdx.x;
    int i = blockIdx.x * 256 + t;
    s[t] = (i < n) ? deg[i] : 0;
    __syncthreads();
    for (int st = 128; st > 0; st >>= 1) {
        if (t < st) s[t] += s[t + st];
        __syncthreads();
    }
    if (t == 0) bsum[blockIdx.x] = s[0];
}

__global__ __launch_bounds__(512) void scan_block_kernel(int* __restrict__ bsum,
                                                         int* __restrict__ off,
                                                         int nblk, int n) {
    __shared__ int s[512];
    int t = threadIdx.x;
    int v = (t < nblk) ? bsum[t] : 0;
    s[t] = v;
    __syncthreads();
    for (int st = 1; st < 512; st <<= 1) {
        int a = (t >= st) ? s[t - st] : 0;
        __syncthreads();
        s[t] += a;
        __syncthreads();
    }
    if (t < nblk) bsum[t] = s[t] - v;  // exclusive
    if (t == 511) off[n] = s[511];     // total = E
}

__global__ __launch_bounds__(256) void scan_final_kernel(const int* __restrict__ deg,
                                                         const int* __restrict__ bsum,
                                                         int* __restrict__ off, int n) {
    __shared__ int s[256];
    int t = threadIdx.x;
    int i = blockIdx.x * 256 + t;
    int v = (i < n) ? deg[i] : 0;
    s[t] = v;
    __syncthreads();
    for (int st = 1; st < 256; st <<= 1) {
        int a = (t >= st) ? s[t - st] : 0;
        __syncthreads();
        s[t] += a;
        __syncthreads();
    }
    if (i < n) off[i] = bsum[blockIdx.x] + s[t] - v;
}

// R6 direct scatter (R8 buckets, R9 row-sweeps, R11 col-sweeps all net-regressed)
__global__ void csr_scatter_kernel(const int* __restrict__ row, const int* __restrict__ col,
                                   const float* __restrict__ dis, const int* __restrict__ off,
                                   int* __restrict__ cursor, int2* __restrict__ ecsr, int E) {
    int e = blockIdx.x * 256 + threadIdx.x;
    if (e < E) {
        int r = row[e], c = col[e];
        float w = dis[r] * dis[c];
        int pos = atomicAdd(&cursor[r], 1);
        int2 p;
        p.x = c;
        p.y = __float_as_int(w);
        ecsr[(size_t)off[r] + pos] = p;
    }
}

// ---------------- MLP ----------------
// GEMM1, R12: B fragments loaded DIRECTLY from w1T (16B contiguous per frag;
// per k-step a block touches 16KB of w1T -> L1-served). Kills Bs LDS (25.6->5KB,
// R11 counters: occupancy 25%, 2.4M bank conflicts from Bs staging stores).
__global__ __launch_bounds__(256) void gemm1_kernel(const float* __restrict__ x,
                                                    const unsigned short* __restrict__ w1T,
                                                    const float* __restrict__ b1,
                                                    unsigned short* __restrict__ h1, int M) {
    __shared__ unsigned short As[64][40];

    const int tid = threadIdx.x;
    const int lane = tid & 63;
    const int w = tid >> 6;
    const int wr = w >> 1, wc = w & 1;          // wave tile: rows wr*32, cols wc*128
    const int row0 = blockIdx.x * 64;

    const int am = tid >> 2;
    const int ak = (tid & 3) * 8;
    const int fr = lane & 15;
    const int ko = (lane >> 4) * 8;

    f32x4 acc[2][8] = {};

    for (int kk = 0; kk < 256; kk += 32) {
        {
            int gr = row0 + am;
            u16x8 av;
            if (gr < M) {
                const float* p = x + (size_t)gr * IN_DIM_ + kk + ak;
                #pragma unroll
                for (int j = 0; j < 8; ++j) av[j] = f2bf(p[j]);
            } else {
                #pragma unroll
                for (int j = 0; j < 8; ++j) av[j] = 0;
            }
            *(u16x8*)&As[am][ak] = av;
        }
        __syncthreads();

        bf16x8 a[2];
        #pragma unroll
        for (int mi = 0; mi < 2; ++mi) a[mi] = *(const bf16x8*)&As[wr * 32 + mi * 16 + fr][ko];
        bf16x8 b[8];
        #pragma unroll
        for (int ni = 0; ni < 8; ++ni)
            b[ni] = *(const bf16x8*)&w1T[(size_t)(wc * 128 + ni * 16 + fr) * 256 + kk + ko];
        #pragma unroll
        for (int ni = 0; ni < 8; ++ni) {
            #pragma unroll
            for (int mi = 0; mi < 2; ++mi)
                acc[mi][ni] = __builtin_amdgcn_mfma_f32_16x16x32_bf16(a[mi], b[ni], acc[mi][ni], 0, 0, 0);
        }
        __syncthreads();
    }

    const int rg = (lane >> 4) * 4;
    #pragma unroll
    for (int mi = 0; mi < 2; ++mi) {
        #pragma unroll
        for (int r = 0; r < 4; ++r) {
            int gm = row0 + wr * 32 + mi * 16 + rg + r;
            if (gm < M) {
                #pragma unroll
                for (int ni = 0; ni < 8; ++ni) {
                    int gn = wc * 128 + ni * 16 + fr;
                    float v = acc[mi][ni][r] + b1[gn];
                    v = fmaxf(v, 0.f);
                    h1[(size_t)gm * HID_ + gn] = f2bf(v);
                }
            }
        }
    }
}

// GEMM2: h = h1 @ W2 + b2 -> h bf16 [M,64]; out = gamma0*h (f32 pre-rounding)
// B also loaded direct from w2T (same 16B-contiguous fragment trick, only 32KB)
__global__ __launch_bounds__(256) void gemm2_kernel(const unsigned short* __restrict__ h1,
                                                    const unsigned short* __restrict__ w2T,
                                                    const float* __restrict__ b2,
                                                    const float* __restrict__ gamma,
                                                    unsigned short* __restrict__ h,
                                                    float* __restrict__ out, int M) {
    __shared__ unsigned short As[64][40];

    const int tid = threadIdx.x;
    const int lane = tid & 63;
    const int w = tid >> 6;
    const int wr = w >> 1, wc = w & 1;
    const int row0 = blockIdx.x * 64;

    const int am = tid >> 2;
    const int ak = (tid & 3) * 8;
    const int fr = lane & 15;
    const int ko = (lane >> 4) * 8;

    f32x4 acc[2][2] = {};

    for (int kk = 0; kk < 256; kk += 32) {
        {
            int gr = row0 + am;
            if (gr < M) {
                *(u16x8*)&As[am][ak] = *(const u16x8*)&h1[(size_t)gr * HID_ + kk + ak];
            } else {
                u16x8 z = {};
                *(u16x8*)&As[am][ak] = z;
            }
        }
        __syncthreads();

        bf16x8 a[2], b[2];
        #pragma unroll
        for (int mi = 0; mi < 2; ++mi) a[mi] = *(const bf16x8*)&As[wr * 32 + mi * 16 + fr][ko];
        #pragma unroll
        for (int ni = 0; ni < 2; ++ni)
            b[ni] = *(const bf16x8*)&w2T[(size_t)(wc * 32 + ni * 16 + fr) * 256 + kk + ko];
        #pragma unroll
        for (int mi = 0; mi < 2; ++mi)
            #pragma unroll
            for (int ni = 0; ni < 2; ++ni)
                acc[mi][ni] = __builtin_amdgcn_mfma_f32_16x16x32_bf16(a[mi], b[ni], acc[mi][ni], 0, 0, 0);
        __syncthreads();
    }

    const float g0 = gamma[0];
    const int rg = (lane >> 4) * 4;
    #pragma unroll
    for (int mi = 0; mi < 2; ++mi) {
        #pragma unroll
        for (int r = 0; r < 4; ++r) {
            int gm = row0 + wr * 32 + mi * 16 + rg + r;
            if (gm < M) {
                #pragma unroll
                for (int ni = 0; ni < 2; ++ni) {
                    int gn = wc * 32 + ni * 16 + fr;
                    float v = acc[mi][ni][r] + b2[gn];
                    h[(size_t)gm * OUT_ + gn] = f2bf(v);
                    out[(size_t)gm * OUT_ + gn] = g0 * v;
                }
            }
        }
    }
}

// ---------------- propagation: R6 pull + window-2 fusion; last hn store skipped ----------------
__global__ __launch_bounds__(256) void pull_kernel(const int* __restrict__ off,
                                                   const int2* __restrict__ ecsr,
                                                   const unsigned short* __restrict__ hc,
                                                   unsigned short* __restrict__ hn,
                                                   float* __restrict__ out,
                                                   const float* __restrict__ gamma,
                                                   int k, int fuse, int n) {
    int node = blockIdx.x * 4 + (threadIdx.x >> 6);
    if (node >= n) return;
    int lane = threadIdx.x & 63;
    int half = lane >> 5;
    int fl = (lane & 31) * 2;
    int s = off[node], e = off[node + 1];
    float acc0 = 0.f, acc1 = 0.f;

    int j = s + half;
    // 8 edges per half per iteration -> 8 outstanding gathers per lane
    for (; j + 14 < e; j += 16) {
        int2 p0 = ecsr[j],      p1 = ecsr[j + 2],  p2 = ecsr[j + 4],  p3 = ecsr[j + 6];
        int2 p4 = ecsr[j + 8],  p5 = ecsr[j + 10], p6 = ecsr[j + 12], p7 = ecsr[j + 14];
        unsigned int v0 = *(const unsigned int*)&hc[(size_t)p0.x * OUT_ + fl];
        unsigned int v1 = *(const unsigned int*)&hc[(size_t)p1.x * OUT_ + fl];
        unsigned int v2 = *(const unsigned int*)&hc[(size_t)p2.x * OUT_ + fl];
        unsigned int v3 = *(const unsigned int*)&hc[(size_t)p3.x * OUT_ + fl];
        unsigned int v4 = *(const unsigned int*)&hc[(size_t)p4.x * OUT_ + fl];
        unsigned int v5 = *(const unsigned int*)&hc[(size_t)p5.x * OUT_ + fl];
        unsigned int v6 = *(const unsigned int*)&hc[(size_t)p6.x * OUT_ + fl];
        unsigned int v7 = *(const unsigned int*)&hc[(size_t)p7.x * OUT_ + fl];
        float w0 = __int_as_float(p0.y), w1 = __int_as_float(p1.y);
        float w2 = __int_as_float(p2.y), w3 = __int_as_float(p3.y);
        float w4 = __int_as_float(p4.y), w5 = __int_as_float(p5.y);
        float w6 = __int_as_float(p6.y), w7 = __int_as_float(p7.y);
        acc0 += w0 * bflo(v0); acc1 += w0 * bfhi(v0);
        acc0 += w1 * bflo(v1); acc1 += w1 * bfhi(v1);
        acc0 += w2 * bflo(v2); acc1 += w2 * bfhi(v2);
        acc0 += w3 * bflo(v3); acc1 += w3 * bfhi(v3);
        acc0 += w4 * bflo(v4); acc1 += w4 * bfhi(v4);
        acc0 += w5 * bflo(v5); acc1 += w5 * bfhi(v5);
        acc0 += w6 * bflo(v6); acc1 += w6 * bfhi(v6);
        acc0 += w7 * bflo(v7); acc1 += w7 * bfhi(v7);
    }
    for (; j + 2 < e; j += 4) {
        int2 pa = ecsr[j], pb = ecsr[j + 2];
        unsigned int va = *(const unsigned int*)&hc[(size_t)pa.x * OUT_ + fl];
        unsigned int vb = *(const unsigned int*)&hc[(size_t)pb.x * OUT_ + fl];
        float wa = __int_as_float(pa.y), wb = __int_as_float(pb.y);
        acc0 += wa * bflo(va); acc1 += wa * bfhi(va);
        acc0 += wb * bflo(vb); acc1 += wb * bfhi(vb);
    }
    if (j < e) {
        int2 p = ecsr[j];
        unsigned int v = *(const unsigned int*)&hc[(size_t)p.x * OUT_ + fl];
        float w = __int_as_float(p.y);
        acc0 += w * bflo(v);
        acc1 += w * bfhi(v);
    }

    acc0 += __shfl_xor(acc0, 32);
    acc1 += __shfl_xor(acc1, 32);

    if (lane < 32) {
        size_t o = (size_t)node * OUT_ + fl;
        if (k < KSTEPS) {  // h_K itself is never re-read; only its gamma-term matters
            unsigned int packed = (unsigned int)f2bf(acc0) | ((unsigned int)f2bf(acc1) << 16);
            *(unsigned int*)&hn[o] = packed;
        }
        if (fuse) {
            float gp = gamma[k - 1], gc = gamma[k];
            unsigned int hown = *(const unsigned int*)&hc[o];  // own row h_{k-1}[node]
            float2* op = (float2*)&out[o];
            float2 ov = *op;
            ov.x += gp * bflo(hown) + gc * acc0;
            ov.y += gp * bfhi(hown) + gc * acc1;
            *op = ov;
        }
    }
}

// ---------------- launcher ----------------
extern "C" void kernel_launch(void* const* d_in, const int* in_sizes, int n_in,
                              void* d_out, int out_size, void* d_ws, size_t ws_size,
                              hipStream_t stream) {
    const float* x = (const float*)d_in[0];
    const int* ei = (const int*)d_in[1];
    const float* W1 = (const float*)d_in[2];
    const float* b1 = (const float*)d_in[3];
    const float* W2 = (const float*)d_in[4];
    const float* b2 = (const float*)d_in[5];
    const float* alpha = (const float*)d_in[6];
    const int* row = ei;
    const int* col = ei + N_EDGES;
    float* out = (float*)d_out;

    const int NBLK = (N_NODES + 255) / 256;   // 391

    char* wsb = (char*)d_ws;
    size_t p = 0;
    auto alloc = [&](size_t bytes) { size_t r = p; p += (bytes + 255) & ~255ull; return r; };
    float* gamma = (float*)(wsb + alloc(16 * 4));
    int* off     = (int*)(wsb + alloc((N_NODES + 1) * 4));
    int* cursor  = (int*)(wsb + alloc(N_NODES * 4));
    int* deg     = (int*)(wsb + alloc(N_NODES * 4));
    float* dis   = (float*)(wsb + alloc(N_NODES * 4));
    int* bsum    = (int*)(wsb + alloc(512 * 4));
    unsigned short* w1T = (unsigned short*)(wsb + alloc((size_t)IN_DIM_ * HID_ * 2));
    unsigned short* w2T = (unsigned short*)(wsb + alloc((size_t)HID_ * OUT_ * 2));
    int2* ecsr   = (int2*)(wsb + alloc((size_t)N_EDGES * 8));
    unsigned short* h1  = (unsigned short*)(wsb + alloc((size_t)N_NODES * HID_ * 2)); // 51.2MB
    unsigned short* h_a = (unsigned short*)(wsb + alloc((size_t)N_NODES * OUT_ * 2)); // 12.8MB
    unsigned short* h_b = h1;  // h1 dead after gemm2

    hipMemsetAsync(cursor, 0, N_NODES * sizeof(int), stream);
    hipMemsetAsync(deg, 0, N_NODES * sizeof(int), stream);
    gamma_kernel<<<1, 64, 0, stream>>>(alpha, gamma);
    deg_kernel<<<(N_EDGES + 255) / 256, 256, 0, stream>>>(row, deg, N_EDGES);
    dis_kernel<<<NBLK, 256, 0, stream>>>(deg, dis, N_NODES);
    scan_sum_kernel<<<NBLK, 256, 0, stream>>>(deg, bsum, N_NODES);
    scan_block_kernel<<<1, 512, 0, stream>>>(bsum, off, NBLK, N_NODES);
    scan_final_kernel<<<NBLK, 256, 0, stream>>>(deg, bsum, off, N_NODES);
    csr_scatter_kernel<<<(N_EDGES + 255) / 256, 256, 0, stream>>>(row, col, dis, off, cursor,
                                                                  ecsr, N_EDGES);
    wcast_kernel<<<dim3(1, HID_), 256, 0, stream>>>(W1, w1T, IN_DIM_, HID_);
    wcast_kernel<<<dim3(1, OUT_), 256, 0, stream>>>(W2, w2T, HID_, OUT_);

    gemm1_kernel<<<(N_NODES + 63) / 64, 256, 0, stream>>>(x, w1T, b1, h1, N_NODES);
    gemm2_kernel<<<(N_NODES + 63) / 64, 256, 0, stream>>>(h1, w2T, b2, gamma, h_a, out, N_NODES);

    unsigned short* hc = h_a;
    unsigned short* hn = h_b;
    for (int k = 1; k <= KSTEPS; ++k) {
        int fuse = (k % 2 == 0);  // even steps fold gamma_{k-1} and gamma_k into out
        pull_kernel<<<(N_NODES + 3) / 4, 256, 0, stream>>>(off, ecsr, hc, hn, out, gamma, k,
                                                           fuse, N_NODES);
        unsigned short* t = hc; hc = hn; hn = t;
    }
}

// Round 13
// 788.728 us; speedup vs baseline: 1.0379x; 1.0234x over previous
//
#include <hip/hip_runtime.h>
#include <hip/hip_bf16.h>

#define N_NODES 100000
#define N_EDGES 1600000
#define IN_DIM_ 256
#define HID_ 256
#define OUT_ 64
#define KSTEPS 10

typedef __attribute__((ext_vector_type(4))) float f32x4;
typedef __attribute__((ext_vector_type(8))) __bf16 bf16x8;
typedef __attribute__((ext_vector_type(8))) unsigned short u16x8;

static __device__ __forceinline__ unsigned short f2bf(float f) {
    union { float f; unsigned int u; } v; v.f = f;
    unsigned int u = v.u;
    unsigned int r = u + 0x7FFFu + ((u >> 16) & 1u);  // RNE
    return (unsigned short)(r >> 16);
}
static __device__ __forceinline__ float bflo(unsigned int v) {
    return __uint_as_float(v << 16);
}
static __device__ __forceinline__ float bfhi(unsigned int v) {
    return __uint_as_float(v & 0xFFFF0000u);
}

// ---------------- small setup kernels ----------------

__global__ void gamma_kernel(const float* __restrict__ alpha, float* __restrict__ gamma) {
    if (threadIdx.x == 0) {
        float m = alpha[0];
        for (int i = 1; i <= KSTEPS; ++i) m = fmaxf(m, alpha[i]);
        float e[KSTEPS + 1];
        float s = 0.f;
        for (int i = 0; i <= KSTEPS; ++i) { e[i] = expf(alpha[i] - m); s += e[i]; }
        float inv = 1.f / s;
        for (int i = 0; i <= KSTEPS; ++i) gamma[i] = e[i] * inv;
    }
}

__global__ void deg_kernel(const int* __restrict__ row, int* __restrict__ deg, int E) {
    int e = blockIdx.x * 256 + threadIdx.x;
    if (e < E) atomicAdd(&deg[row[e]], 1);
}

__global__ void dis_kernel(const int* __restrict__ deg, float* __restrict__ dis, int n) {
    int i = blockIdx.x * 256 + threadIdx.x;
    if (i < n) {
        int d = deg[i];
        dis[i] = d > 0 ? rsqrtf((float)d) : 0.f;
    }
}

// transpose+cast weights once: wT[n][k] = bf16(W[k][n])
__global__ void wcast_kernel(const float* __restrict__ W, unsigned short* __restrict__ wT,
                             int K, int N) {
    int k = blockIdx.x * 256 + threadIdx.x;
    int n = blockIdx.y;
    if (k < K) wT[(size_t)n * K + k] = f2bf(W[(size_t)k * N + n]);
}

// R13: pre-cast x f32 -> bf16 once (pure BW, ~28us). gemm1's A-staging becomes a
// bare vector copy (R12 lesson: f2bf+f32-loads in the k-loop staging path is the
// latency bottleneck, not VALU throughput) and gemm1 read traffic halves.
__global__ __launch_bounds__(256) void xcast_kernel(const float* __restrict__ x,
                                                    unsigned short* __restrict__ xb, int n8) {
    int i = blockIdx.x * 256 + threadIdx.x;
    if (i < n8) {
        const float* p = x + (size_t)i * 8;
        u16x8 v;
        #pragma unroll
        for (int j = 0; j < 8; ++j) v[j] = f2bf(p[j]);
        *(u16x8*)&xb[(size_t)i * 8] = v;
    }
}

// ---------------- hierarchical scan ----------------

__global__ __launch_bounds__(256) void scan_sum_kernel(const int* __restrict__ deg,
                                                       int* __restrict__ bsum, int n) {
    __shared__ int s[256];
    int t = threadIdx.x;
    int i = blockIdx.x * 256 + t;
    s[t] = (i < n) ? deg[i] : 0;
    __syncthreads();
    for (int st = 128; st > 0; st >>= 1) {
        if (t < st) s[t] += s[t + st];
        __syncthreads();
    }
    if (t == 0) bsum[blockIdx.x] = s[0];
}

__global__ __launch_bounds__(512) void scan_block_kernel(int* __restrict__ bsum,
                                                         int* __restrict__ off,
                                                         int nblk, int n) {
    __shared__ int s[512];
    int t = threadIdx.x;
    int v = (t < nblk) ? bsum[t] : 0;
    s[t] = v;
    __syncthreads();
    for (int st = 1; st < 512; st <<= 1) {
        int a = (t >= st) ? s[t - st] : 0;
        __syncthreads();
        s[t] += a;
        __syncthreads();
    }
    if (t < nblk) bsum[t] = s[t] - v;  // exclusive
    if (t == 511) off[n] = s[511];     // total = E
}

__global__ __launch_bounds__(256) void scan_final_kernel(const int* __restrict__ deg,
                                                         const int* __restrict__ bsum,
                                                         int* __restrict__ off, int n) {
    __shared__ int s[256];
    int t = threadIdx.x;
    int i = blockIdx.x * 256 + t;
    int v = (i < n) ? deg[i] : 0;
    s[t] = v;
    __syncthreads();
    for (int st = 1; st < 256; st <<= 1) {
        int a = (t >= st) ? s[t - st] : 0;
        __syncthreads();
        s[t] += a;
        __syncthreads();
    }
    if (i < n) off[i] = bsum[blockIdx.x] + s[t] - v;
}

// R6 direct scatter (R8 buckets, R9 row-sweeps, R11 col-sweeps all net-regressed)
__global__ void csr_scatter_kernel(const int* __restrict__ row, const int* __restrict__ col,
                                   const float* __restrict__ dis, const int* __restrict__ off,
                                   int* __restrict__ cursor, int2* __restrict__ ecsr, int E) {
    int e = blockIdx.x * 256 + threadIdx.x;
    if (e < E) {
        int r = row[e], c = col[e];
        float w = dis[r] * dis[c];
        int pos = atomicAdd(&cursor[r], 1);
        int2 p;
        p.x = c;
        p.y = __float_as_int(w);
        ecsr[(size_t)off[r] + pos] = p;
    }
}

// ---------------- MLP ----------------
// GEMM1, R13: 128 rows x 256 cols per 512-thread block (8 waves, 4x2).
// A from pre-cast xb via u16x8 copies; B staged to LDS (R12: direct-B regressed).
__global__ __launch_bounds__(512) void gemm1_kernel(const unsigned short* __restrict__ xb,
                                                    const unsigned short* __restrict__ w1T,
                                                    const float* __restrict__ b1,
                                                    unsigned short* __restrict__ h1, int M) {
    __shared__ unsigned short As[128][40];
    __shared__ unsigned short Bs[256][40];

    const int tid = threadIdx.x;
    const int lane = tid & 63;
    const int w = tid >> 6;                     // 0..7
    const int wr = w >> 1, wc = w & 1;          // wave tile: rows wr*32, cols wc*128
    const int row0 = blockIdx.x * 128;

    const int am = tid >> 2;                    // 0..127
    const int ak = (tid & 3) * 8;               // 0,8,16,24
    const int bn = tid >> 1;                    // 0..255
    const int bh = (tid & 1) * 16;              // 0,16
    const int fr = lane & 15;
    const int ko = (lane >> 4) * 8;

    f32x4 acc[2][8] = {};

    for (int kk = 0; kk < 256; kk += 32) {
        {
            int gr = row0 + am;
            if (gr < M) {
                *(u16x8*)&As[am][ak] = *(const u16x8*)&xb[(size_t)gr * IN_DIM_ + kk + ak];
            } else {
                u16x8 z = {};
                *(u16x8*)&As[am][ak] = z;
            }
        }
        {
            const unsigned short* p = &w1T[(size_t)bn * 256 + kk + bh];
            *(u16x8*)&Bs[bn][bh]     = *(const u16x8*)&p[0];
            *(u16x8*)&Bs[bn][bh + 8] = *(const u16x8*)&p[8];
        }
        __syncthreads();

        bf16x8 a[2];
        #pragma unroll
        for (int mi = 0; mi < 2; ++mi) a[mi] = *(const bf16x8*)&As[wr * 32 + mi * 16 + fr][ko];
        #pragma unroll
        for (int ni = 0; ni < 8; ++ni) {
            bf16x8 b = *(const bf16x8*)&Bs[wc * 128 + ni * 16 + fr][ko];
            #pragma unroll
            for (int mi = 0; mi < 2; ++mi)
                acc[mi][ni] = __builtin_amdgcn_mfma_f32_16x16x32_bf16(a[mi], b, acc[mi][ni], 0, 0, 0);
        }
        __syncthreads();
    }

    const int rg = (lane >> 4) * 4;
    #pragma unroll
    for (int mi = 0; mi < 2; ++mi) {
        #pragma unroll
        for (int r = 0; r < 4; ++r) {
            int gm = row0 + wr * 32 + mi * 16 + rg + r;
            if (gm < M) {
                #pragma unroll
                for (int ni = 0; ni < 8; ++ni) {
                    int gn = wc * 128 + ni * 16 + fr;
                    float v = acc[mi][ni][r] + b1[gn];
                    v = fmaxf(v, 0.f);
                    h1[(size_t)gm * HID_ + gn] = f2bf(v);
                }
            }
        }
    }
}

// GEMM2 (R11 proven form): h = h1 @ W2 + b2 -> h bf16; out = gamma0*h
__global__ __launch_bounds__(256) void gemm2_kernel(const unsigned short* __restrict__ h1,
                                                    const unsigned short* __restrict__ w2T,
                                                    const float* __restrict__ b2,
                                                    const float* __restrict__ gamma,
                                                    unsigned short* __restrict__ h,
                                                    float* __restrict__ out, int M) {
    __shared__ unsigned short As[64][40];
    __shared__ unsigned short Bs[64][40];

    const int tid = threadIdx.x;
    const int lane = tid & 63;
    const int w = tid >> 6;
    const int wr = w >> 1, wc = w & 1;
    const int row0 = blockIdx.x * 64;

    const int am = tid >> 2;
    const int ak = (tid & 3) * 8;
    const int fr = lane & 15;
    const int ko = (lane >> 4) * 8;

    f32x4 acc[2][2] = {};

    for (int kk = 0; kk < 256; kk += 32) {
        {
            int gr = row0 + am;
            if (gr < M) {
                *(u16x8*)&As[am][ak] = *(const u16x8*)&h1[(size_t)gr * HID_ + kk + ak];
            } else {
                u16x8 z = {};
                *(u16x8*)&As[am][ak] = z;
            }
        }
        if (tid < 128) {
            int n = tid >> 1, hf = (tid & 1) * 16;
            const unsigned short* p = &w2T[(size_t)n * 256 + kk + hf];
            *(u16x8*)&Bs[n][hf]     = *(const u16x8*)&p[0];
            *(u16x8*)&Bs[n][hf + 8] = *(const u16x8*)&p[8];
        }
        __syncthreads();

        bf16x8 a[2], b[2];
        #pragma unroll
        for (int mi = 0; mi < 2; ++mi) a[mi] = *(const bf16x8*)&As[wr * 32 + mi * 16 + fr][ko];
        #pragma unroll
        for (int ni = 0; ni < 2; ++ni) b[ni] = *(const bf16x8*)&Bs[wc * 32 + ni * 16 + fr][ko];
        #pragma unroll
        for (int mi = 0; mi < 2; ++mi)
            #pragma unroll
            for (int ni = 0; ni < 2; ++ni)
                acc[mi][ni] = __builtin_amdgcn_mfma_f32_16x16x32_bf16(a[mi], b[ni], acc[mi][ni], 0, 0, 0);
        __syncthreads();
    }

    const float g0 = gamma[0];
    const int rg = (lane >> 4) * 4;
    #pragma unroll
    for (int mi = 0; mi < 2; ++mi) {
        #pragma unroll
        for (int r = 0; r < 4; ++r) {
            int gm = row0 + wr * 32 + mi * 16 + rg + r;
            if (gm < M) {
                #pragma unroll
                for (int ni = 0; ni < 2; ++ni) {
                    int gn = wc * 32 + ni * 16 + fr;
                    float v = acc[mi][ni][r] + b2[gn];
                    h[(size_t)gm * OUT_ + gn] = f2bf(v);
                    out[(size_t)gm * OUT_ + gn] = g0 * v;
                }
            }
        }
    }
}

// ---------------- propagation: R6 pull + window-2 fusion; last hn store skipped ----------------
__global__ __launch_bounds__(256) void pull_kernel(const int* __restrict__ off,
                                                   const int2* __restrict__ ecsr,
                                                   const unsigned short* __restrict__ hc,
                                                   unsigned short* __restrict__ hn,
                                                   float* __restrict__ out,
                                                   const float* __restrict__ gamma,
                                                   int k, int fuse, int n) {
    int node = blockIdx.x * 4 + (threadIdx.x >> 6);
    if (node >= n) return;
    int lane = threadIdx.x & 63;
    int half = lane >> 5;
    int fl = (lane & 31) * 2;
    int s = off[node], e = off[node + 1];
    float acc0 = 0.f, acc1 = 0.f;

    int j = s + half;
    // 8 edges per half per iteration -> 8 outstanding gathers per lane
    for (; j + 14 < e; j += 16) {
        int2 p0 = ecsr[j],      p1 = ecsr[j + 2],  p2 = ecsr[j + 4],  p3 = ecsr[j + 6];
        int2 p4 = ecsr[j + 8],  p5 = ecsr[j + 10], p6 = ecsr[j + 12], p7 = ecsr[j + 14];
        unsigned int v0 = *(const unsigned int*)&hc[(size_t)p0.x * OUT_ + fl];
        unsigned int v1 = *(const unsigned int*)&hc[(size_t)p1.x * OUT_ + fl];
        unsigned int v2 = *(const unsigned int*)&hc[(size_t)p2.x * OUT_ + fl];
        unsigned int v3 = *(const unsigned int*)&hc[(size_t)p3.x * OUT_ + fl];
        unsigned int v4 = *(const unsigned int*)&hc[(size_t)p4.x * OUT_ + fl];
        unsigned int v5 = *(const unsigned int*)&hc[(size_t)p5.x * OUT_ + fl];
        unsigned int v6 = *(const unsigned int*)&hc[(size_t)p6.x * OUT_ + fl];
        unsigned int v7 = *(const unsigned int*)&hc[(size_t)p7.x * OUT_ + fl];
        float w0 = __int_as_float(p0.y), w1 = __int_as_float(p1.y);
        float w2 = __int_as_float(p2.y), w3 = __int_as_float(p3.y);
        float w4 = __int_as_float(p4.y), w5 = __int_as_float(p5.y);
        float w6 = __int_as_float(p6.y), w7 = __int_as_float(p7.y);
        acc0 += w0 * bflo(v0); acc1 += w0 * bfhi(v0);
        acc0 += w1 * bflo(v1); acc1 += w1 * bfhi(v1);
        acc0 += w2 * bflo(v2); acc1 += w2 * bfhi(v2);
        acc0 += w3 * bflo(v3); acc1 += w3 * bfhi(v3);
        acc0 += w4 * bflo(v4); acc1 += w4 * bfhi(v4);
        acc0 += w5 * bflo(v5); acc1 += w5 * bfhi(v5);
        acc0 += w6 * bflo(v6); acc1 += w6 * bfhi(v6);
        acc0 += w7 * bflo(v7); acc1 += w7 * bfhi(v7);
    }
    for (; j + 2 < e; j += 4) {
        int2 pa = ecsr[j], pb = ecsr[j + 2];
        unsigned int va = *(const unsigned int*)&hc[(size_t)pa.x * OUT_ + fl];
        unsigned int vb = *(const unsigned int*)&hc[(size_t)pb.x * OUT_ + fl];
        float wa = __int_as_float(pa.y), wb = __int_as_float(pb.y);
        acc0 += wa * bflo(va); acc1 += wa * bfhi(va);
        acc0 += wb * bflo(vb); acc1 += wb * bfhi(vb);
    }
    if (j < e) {
        int2 p = ecsr[j];
        unsigned int v = *(const unsigned int*)&hc[(size_t)p.x * OUT_ + fl];
        float w = __int_as_float(p.y);
        acc0 += w * bflo(v);
        acc1 += w * bfhi(v);
    }

    acc0 += __shfl_xor(acc0, 32);
    acc1 += __shfl_xor(acc1, 32);

    if (lane < 32) {
        size_t o = (size_t)node * OUT_ + fl;
        if (k < KSTEPS) {  // h_K itself is never re-read; only its gamma-term matters
            unsigned int packed = (unsigned int)f2bf(acc0) | ((unsigned int)f2bf(acc1) << 16);
            *(unsigned int*)&hn[o] = packed;
        }
        if (fuse) {
            float gp = gamma[k - 1], gc = gamma[k];
            unsigned int hown = *(const unsigned int*)&hc[o];  // own row h_{k-1}[node]
            float2* op = (float2*)&out[o];
            float2 ov = *op;
            ov.x += gp * bflo(hown) + gc * acc0;
            ov.y += gp * bfhi(hown) + gc * acc1;
            *op = ov;
        }
    }
}

// ---------------- launcher ----------------
extern "C" void kernel_launch(void* const* d_in, const int* in_sizes, int n_in,
                              void* d_out, int out_size, void* d_ws, size_t ws_size,
                              hipStream_t stream) {
    const float* x = (const float*)d_in[0];
    const int* ei = (const int*)d_in[1];
    const float* W1 = (const float*)d_in[2];
    const float* b1 = (const float*)d_in[3];
    const float* W2 = (const float*)d_in[4];
    const float* b2 = (const float*)d_in[5];
    const float* alpha = (const float*)d_in[6];
    const int* row = ei;
    const int* col = ei + N_EDGES;
    float* out = (float*)d_out;

    const int NBLK = (N_NODES + 255) / 256;   // 391

    char* wsb = (char*)d_ws;
    size_t p = 0;
    auto alloc = [&](size_t bytes) { size_t r = p; p += (bytes + 255) & ~255ull; return r; };
    float* gamma = (float*)(wsb + alloc(16 * 4));
    int* off     = (int*)(wsb + alloc((N_NODES + 1) * 4));
    int* cursor  = (int*)(wsb + alloc(N_NODES * 4));
    int* deg     = (int*)(wsb + alloc(N_NODES * 4));
    float* dis   = (float*)(wsb + alloc(N_NODES * 4));
    int* bsum    = (int*)(wsb + alloc(512 * 4));
    unsigned short* w1T = (unsigned short*)(wsb + alloc((size_t)IN_DIM_ * HID_ * 2));
    unsigned short* w2T = (unsigned short*)(wsb + alloc((size_t)HID_ * OUT_ * 2));
    int2* ecsr   = (int2*)(wsb + alloc((size_t)N_EDGES * 8));
    unsigned short* xb  = (unsigned short*)(wsb + alloc((size_t)N_NODES * IN_DIM_ * 2)); // 51.2MB
    unsigned short* h1  = (unsigned short*)(wsb + alloc((size_t)N_NODES * HID_ * 2));    // 51.2MB
    unsigned short* h_a = (unsigned short*)(wsb + alloc((size_t)N_NODES * OUT_ * 2));    // 12.8MB
    unsigned short* h_b = h1;  // h1 dead after gemm2

    hipMemsetAsync(cursor, 0, N_NODES * sizeof(int), stream);
    hipMemsetAsync(deg, 0, N_NODES * sizeof(int), stream);
    gamma_kernel<<<1, 64, 0, stream>>>(alpha, gamma);
    deg_kernel<<<(N_EDGES + 255) / 256, 256, 0, stream>>>(row, deg, N_EDGES);
    dis_kernel<<<NBLK, 256, 0, stream>>>(deg, dis, N_NODES);
    scan_sum_kernel<<<NBLK, 256, 0, stream>>>(deg, bsum, N_NODES);
    scan_block_kernel<<<1, 512, 0, stream>>>(bsum, off, NBLK, N_NODES);
    scan_final_kernel<<<NBLK, 256, 0, stream>>>(deg, bsum, off, N_NODES);
    csr_scatter_kernel<<<(N_EDGES + 255) / 256, 256, 0, stream>>>(row, col, dis, off, cursor,
                                                                  ecsr, N_EDGES);
    wcast_kernel<<<dim3(1, HID_), 256, 0, stream>>>(W1, w1T, IN_DIM_, HID_);
    wcast_kernel<<<dim3(1, OUT_), 256, 0, stream>>>(W2, w2T, HID_, OUT_);
    xcast_kernel<<<(N_NODES * IN_DIM_ / 8 + 255) / 256, 256, 0, stream>>>(
        x, xb, N_NODES * IN_DIM_ / 8);

    gemm1_kernel<<<(N_NODES + 127) / 128, 512, 0, stream>>>(xb, w1T, b1, h1, N_NODES);
    gemm2_kernel<<<(N_NODES + 63) / 64, 256, 0, stream>>>(h1, w2T, b2, gamma, h_a, out, N_NODES);

    unsigned short* hc = h_a;
    unsigned short* hn = h_b;
    for (int k = 1; k <= KSTEPS; ++k) {
        int fuse = (k % 2 == 0);  // even steps fold gamma_{k-1} and gamma_k into out
        pull_kernel<<<(N_NODES + 3) / 4, 256, 0, stream>>>(off, ecsr, hc, hn, out, gamma, k,
                                                           fuse, N_NODES);
        unsigned short* t = hc; hc = hn; hn = t;
    }
}

// Round 14
// 787.383 us; speedup vs baseline: 1.0397x; 1.0017x over previous
//
#include <hip/hip_runtime.h>
#include <hip/hip_bf16.h>

#define N_NODES 100000
#define N_EDGES 1600000
#define IN_DIM_ 256
#define HID_ 256
#define OUT_ 64
#define KSTEPS 10

typedef __attribute__((ext_vector_type(4))) float f32x4;
typedef __attribute__((ext_vector_type(8))) __bf16 bf16x8;
typedef __attribute__((ext_vector_type(8))) unsigned short u16x8;

static __device__ __forceinline__ unsigned short f2bf(float f) {
    union { float f; unsigned int u; } v; v.f = f;
    unsigned int u = v.u;
    unsigned int r = u + 0x7FFFu + ((u >> 16) & 1u);  // RNE
    return (unsigned short)(r >> 16);
}
static __device__ __forceinline__ float bflo(unsigned int v) {
    return __uint_as_float(v << 16);
}
static __device__ __forceinline__ float bfhi(unsigned int v) {
    return __uint_as_float(v & 0xFFFF0000u);
}

// ---------------- small setup kernels ----------------

__global__ void gamma_kernel(const float* __restrict__ alpha, float* __restrict__ gamma) {
    if (threadIdx.x == 0) {
        float m = alpha[0];
        for (int i = 1; i <= KSTEPS; ++i) m = fmaxf(m, alpha[i]);
        float e[KSTEPS + 1];
        float s = 0.f;
        for (int i = 0; i <= KSTEPS; ++i) { e[i] = expf(alpha[i] - m); s += e[i]; }
        float inv = 1.f / s;
        for (int i = 0; i <= KSTEPS; ++i) gamma[i] = e[i] * inv;
    }
}

__global__ void deg_kernel(const int* __restrict__ row, int* __restrict__ deg, int E) {
    int e = blockIdx.x * 256 + threadIdx.x;
    if (e < E) atomicAdd(&deg[row[e]], 1);
}

__global__ void dis_kernel(const int* __restrict__ deg, float* __restrict__ dis, int n) {
    int i = blockIdx.x * 256 + threadIdx.x;
    if (i < n) {
        int d = deg[i];
        dis[i] = d > 0 ? rsqrtf((float)d) : 0.f;
    }
}

// transpose+cast weights once: wT[n][k] = bf16(W[k][n])
__global__ void wcast_kernel(const float* __restrict__ W, unsigned short* __restrict__ wT,
                             int K, int N) {
    int k = blockIdx.x * 256 + threadIdx.x;
    int n = blockIdx.y;
    if (k < K) wT[(size_t)n * K + k] = f2bf(W[(size_t)k * N + n]);
}

// pre-cast x f32 -> bf16 once (R13 win: staging f2bf was gemm1's latency bottleneck)
__global__ __launch_bounds__(256) void xcast_kernel(const float* __restrict__ x,
                                                    unsigned short* __restrict__ xb, int n8) {
    int i = blockIdx.x * 256 + threadIdx.x;
    if (i < n8) {
        const float* p = x + (size_t)i * 8;
        u16x8 v;
        #pragma unroll
        for (int j = 0; j < 8; ++j) v[j] = f2bf(p[j]);
        *(u16x8*)&xb[(size_t)i * 8] = v;
    }
}

// ---------------- hierarchical scan ----------------

__global__ __launch_bounds__(256) void scan_sum_kernel(const int* __restrict__ deg,
                                                       int* __restrict__ bsum, int n) {
    __shared__ int s[256];
    int t = threadIdx.x;
    int i = blockIdx.x * 256 + t;
    s[t] = (i < n) ? deg[i] : 0;
    __syncthreads();
    for (int st = 128; st > 0; st >>= 1) {
        if (t < st) s[t] += s[t + st];
        __syncthreads();
    }
    if (t == 0) bsum[blockIdx.x] = s[0];
}

__global__ __launch_bounds__(512) void scan_block_kernel(int* __restrict__ bsum,
                                                         int* __restrict__ off,
                                                         int nblk, int n) {
    __shared__ int s[512];
    int t = threadIdx.x;
    int v = (t < nblk) ? bsum[t] : 0;
    s[t] = v;
    __syncthreads();
    for (int st = 1; st < 512; st <<= 1) {
        int a = (t >= st) ? s[t - st] : 0;
        __syncthreads();
        s[t] += a;
        __syncthreads();
    }
    if (t < nblk) bsum[t] = s[t] - v;  // exclusive
    if (t == 511) off[n] = s[511];     // total = E
}

__global__ __launch_bounds__(256) void scan_final_kernel(const int* __restrict__ deg,
                                                         const int* __restrict__ bsum,
                                                         int* __restrict__ off, int n) {
    __shared__ int s[256];
    int t = threadIdx.x;
    int i = blockIdx.x * 256 + t;
    int v = (i < n) ? deg[i] : 0;
    s[t] = v;
    __syncthreads();
    for (int st = 1; st < 256; st <<= 1) {
        int a = (t >= st) ? s[t - st] : 0;
        __syncthreads();
        s[t] += a;
        __syncthreads();
    }
    if (i < n) off[i] = bsum[blockIdx.x] + s[t] - v;
}

// R14: ecsr = col only (4B/edge). h_new[r] = dis[r]*sum(dis[c]*h[c]) with state
// stored premultiplied g=dis*h -> per-edge weight eliminated. Scatter no longer
// reads dis; ~16 same-row edges now fill one 64B line (write lines halve).
__global__ void csr_scatter_kernel(const int* __restrict__ row, const int* __restrict__ col,
                                   const int* __restrict__ off,
                                   int* __restrict__ cursor, int* __restrict__ ecsr, int E) {
    int e = blockIdx.x * 256 + threadIdx.x;
    if (e < E) {
        int r = row[e];
        int pos = atomicAdd(&cursor[r], 1);
        ecsr[(size_t)off[r] + pos] = col[e];
    }
}

// ---------------- MLP ----------------
// GEMM1 (R13 form): 128 rows x 256 cols per 512-thread block (8 waves, 4x2).
__global__ __launch_bounds__(512) void gemm1_kernel(const unsigned short* __restrict__ xb,
                                                    const unsigned short* __restrict__ w1T,
                                                    const float* __restrict__ b1,
                                                    unsigned short* __restrict__ h1, int M) {
    __shared__ unsigned short As[128][40];
    __shared__ unsigned short Bs[256][40];

    const int tid = threadIdx.x;
    const int lane = tid & 63;
    const int w = tid >> 6;                     // 0..7
    const int wr = w >> 1, wc = w & 1;          // wave tile: rows wr*32, cols wc*128
    const int row0 = blockIdx.x * 128;

    const int am = tid >> 2;                    // 0..127
    const int ak = (tid & 3) * 8;               // 0,8,16,24
    const int bn = tid >> 1;                    // 0..255
    const int bh = (tid & 1) * 16;              // 0,16
    const int fr = lane & 15;
    const int ko = (lane >> 4) * 8;

    f32x4 acc[2][8] = {};

    for (int kk = 0; kk < 256; kk += 32) {
        {
            int gr = row0 + am;
            if (gr < M) {
                *(u16x8*)&As[am][ak] = *(const u16x8*)&xb[(size_t)gr * IN_DIM_ + kk + ak];
            } else {
                u16x8 z = {};
                *(u16x8*)&As[am][ak] = z;
            }
        }
        {
            const unsigned short* p = &w1T[(size_t)bn * 256 + kk + bh];
            *(u16x8*)&Bs[bn][bh]     = *(const u16x8*)&p[0];
            *(u16x8*)&Bs[bn][bh + 8] = *(const u16x8*)&p[8];
        }
        __syncthreads();

        bf16x8 a[2];
        #pragma unroll
        for (int mi = 0; mi < 2; ++mi) a[mi] = *(const bf16x8*)&As[wr * 32 + mi * 16 + fr][ko];
        #pragma unroll
        for (int ni = 0; ni < 8; ++ni) {
            bf16x8 b = *(const bf16x8*)&Bs[wc * 128 + ni * 16 + fr][ko];
            #pragma unroll
            for (int mi = 0; mi < 2; ++mi)
                acc[mi][ni] = __builtin_amdgcn_mfma_f32_16x16x32_bf16(a[mi], b, acc[mi][ni], 0, 0, 0);
        }
        __syncthreads();
    }

    const int rg = (lane >> 4) * 4;
    #pragma unroll
    for (int mi = 0; mi < 2; ++mi) {
        #pragma unroll
        for (int r = 0; r < 4; ++r) {
            int gm = row0 + wr * 32 + mi * 16 + rg + r;
            if (gm < M) {
                #pragma unroll
                for (int ni = 0; ni < 8; ++ni) {
                    int gn = wc * 128 + ni * 16 + fr;
                    float v = acc[mi][ni][r] + b1[gn];
                    v = fmaxf(v, 0.f);
                    h1[(size_t)gm * HID_ + gn] = f2bf(v);
                }
            }
        }
    }
}

// GEMM2: h0 = h1 @ W2 + b2; store g0 = bf16(dis*h0); out = gamma0*h0 (f32)
__global__ __launch_bounds__(256) void gemm2_kernel(const unsigned short* __restrict__ h1,
                                                    const unsigned short* __restrict__ w2T,
                                                    const float* __restrict__ b2,
                                                    const float* __restrict__ gamma,
                                                    const float* __restrict__ dis,
                                                    unsigned short* __restrict__ g,
                                                    float* __restrict__ out, int M) {
    __shared__ unsigned short As[64][40];
    __shared__ unsigned short Bs[64][40];

    const int tid = threadIdx.x;
    const int lane = tid & 63;
    const int w = tid >> 6;
    const int wr = w >> 1, wc = w & 1;
    const int row0 = blockIdx.x * 64;

    const int am = tid >> 2;
    const int ak = (tid & 3) * 8;
    const int fr = lane & 15;
    const int ko = (lane >> 4) * 8;

    f32x4 acc[2][2] = {};

    for (int kk = 0; kk < 256; kk += 32) {
        {
            int gr = row0 + am;
            if (gr < M) {
                *(u16x8*)&As[am][ak] = *(const u16x8*)&h1[(size_t)gr * HID_ + kk + ak];
            } else {
                u16x8 z = {};
                *(u16x8*)&As[am][ak] = z;
            }
        }
        if (tid < 128) {
            int n = tid >> 1, hf = (tid & 1) * 16;
            const unsigned short* p = &w2T[(size_t)n * 256 + kk + hf];
            *(u16x8*)&Bs[n][hf]     = *(const u16x8*)&p[0];
            *(u16x8*)&Bs[n][hf + 8] = *(const u16x8*)&p[8];
        }
        __syncthreads();

        bf16x8 a[2], b[2];
        #pragma unroll
        for (int mi = 0; mi < 2; ++mi) a[mi] = *(const bf16x8*)&As[wr * 32 + mi * 16 + fr][ko];
        #pragma unroll
        for (int ni = 0; ni < 2; ++ni) b[ni] = *(const bf16x8*)&Bs[wc * 32 + ni * 16 + fr][ko];
        #pragma unroll
        for (int mi = 0; mi < 2; ++mi)
            #pragma unroll
            for (int ni = 0; ni < 2; ++ni)
                acc[mi][ni] = __builtin_amdgcn_mfma_f32_16x16x32_bf16(a[mi], b[ni], acc[mi][ni], 0, 0, 0);
        __syncthreads();
    }

    const float g0 = gamma[0];
    const int rg = (lane >> 4) * 4;
    #pragma unroll
    for (int mi = 0; mi < 2; ++mi) {
        #pragma unroll
        for (int r = 0; r < 4; ++r) {
            int gm = row0 + wr * 32 + mi * 16 + rg + r;
            if (gm < M) {
                float dr = dis[gm];
                #pragma unroll
                for (int ni = 0; ni < 2; ++ni) {
                    int gn = wc * 32 + ni * 16 + fr;
                    float v = acc[mi][ni][r] + b2[gn];
                    g[(size_t)gm * OUT_ + gn] = f2bf(dr * v);
                    out[(size_t)gm * OUT_ + gn] = g0 * v;
                }
            }
        }
    }
}

// ---------------- propagation: weightless pull on premultiplied state ----------------
// t = sum over edges of g[col] (pure adds); h = dis[node]*t (f32);
// out += gamma_k*h; g_new = bf16(dis[node]*h). ecsr is 4B cols only.
__global__ __launch_bounds__(256) void pull_kernel(const int* __restrict__ off,
                                                   const int* __restrict__ ecsr,
                                                   const float* __restrict__ dis,
                                                   const unsigned short* __restrict__ gc,
                                                   unsigned short* __restrict__ gn,
                                                   float* __restrict__ out,
                                                   const float* __restrict__ gamma,
                                                   int k, int n) {
    int node = blockIdx.x * 4 + (threadIdx.x >> 6);
    if (node >= n) return;
    int lane = threadIdx.x & 63;
    int half = lane >> 5;
    int fl = (lane & 31) * 2;
    int s = off[node], e = off[node + 1];
    float acc0 = 0.f, acc1 = 0.f;

    int j = s + half;
    // 8 edges per half per iteration -> 8 outstanding gathers per lane
    for (; j + 14 < e; j += 16) {
        int c0 = ecsr[j],      c1 = ecsr[j + 2],  c2 = ecsr[j + 4],  c3 = ecsr[j + 6];
        int c4 = ecsr[j + 8],  c5 = ecsr[j + 10], c6 = ecsr[j + 12], c7 = ecsr[j + 14];
        unsigned int v0 = *(const unsigned int*)&gc[(size_t)c0 * OUT_ + fl];
        unsigned int v1 = *(const unsigned int*)&gc[(size_t)c1 * OUT_ + fl];
        unsigned int v2 = *(const unsigned int*)&gc[(size_t)c2 * OUT_ + fl];
        unsigned int v3 = *(const unsigned int*)&gc[(size_t)c3 * OUT_ + fl];
        unsigned int v4 = *(const unsigned int*)&gc[(size_t)c4 * OUT_ + fl];
        unsigned int v5 = *(const unsigned int*)&gc[(size_t)c5 * OUT_ + fl];
        unsigned int v6 = *(const unsigned int*)&gc[(size_t)c6 * OUT_ + fl];
        unsigned int v7 = *(const unsigned int*)&gc[(size_t)c7 * OUT_ + fl];
        acc0 += bflo(v0); acc1 += bfhi(v0);
        acc0 += bflo(v1); acc1 += bfhi(v1);
        acc0 += bflo(v2); acc1 += bfhi(v2);
        acc0 += bflo(v3); acc1 += bfhi(v3);
        acc0 += bflo(v4); acc1 += bfhi(v4);
        acc0 += bflo(v5); acc1 += bfhi(v5);
        acc0 += bflo(v6); acc1 += bfhi(v6);
        acc0 += bflo(v7); acc1 += bfhi(v7);
    }
    for (; j + 2 < e; j += 4) {
        int ca = ecsr[j], cb = ecsr[j + 2];
        unsigned int va = *(const unsigned int*)&gc[(size_t)ca * OUT_ + fl];
        unsigned int vb = *(const unsigned int*)&gc[(size_t)cb * OUT_ + fl];
        acc0 += bflo(va); acc1 += bfhi(va);
        acc0 += bflo(vb); acc1 += bfhi(vb);
    }
    if (j < e) {
        int c = ecsr[j];
        unsigned int v = *(const unsigned int*)&gc[(size_t)c * OUT_ + fl];
        acc0 += bflo(v);
        acc1 += bfhi(v);
    }

    acc0 += __shfl_xor(acc0, 32);
    acc1 += __shfl_xor(acc1, 32);

    if (lane < 32) {
        float dr = dis[node];
        float h0 = dr * acc0, h1v = dr * acc1;   // h_k (f32, exact for out)
        size_t o = (size_t)node * OUT_ + fl;
        if (k < KSTEPS) {  // g_K never re-read
            unsigned int packed = (unsigned int)f2bf(dr * h0) |
                                  ((unsigned int)f2bf(dr * h1v) << 16);
            *(unsigned int*)&gn[o] = packed;
        }
        float gk = gamma[k];
        float2* op = (float2*)&out[o];
        float2 ov = *op;
        ov.x += gk * h0;
        ov.y += gk * h1v;
        *op = ov;
    }
}

// ---------------- launcher ----------------
extern "C" void kernel_launch(void* const* d_in, const int* in_sizes, int n_in,
                              void* d_out, int out_size, void* d_ws, size_t ws_size,
                              hipStream_t stream) {
    const float* x = (const float*)d_in[0];
    const int* ei = (const int*)d_in[1];
    const float* W1 = (const float*)d_in[2];
    const float* b1 = (const float*)d_in[3];
    const float* W2 = (const float*)d_in[4];
    const float* b2 = (const float*)d_in[5];
    const float* alpha = (const float*)d_in[6];
    const int* row = ei;
    const int* col = ei + N_EDGES;
    float* out = (float*)d_out;

    const int NBLK = (N_NODES + 255) / 256;   // 391

    char* wsb = (char*)d_ws;
    size_t p = 0;
    auto alloc = [&](size_t bytes) { size_t r = p; p += (bytes + 255) & ~255ull; return r; };
    float* gamma = (float*)(wsb + alloc(16 * 4));
    int* off     = (int*)(wsb + alloc((N_NODES + 1) * 4));
    int* cursor  = (int*)(wsb + alloc(N_NODES * 4));
    int* deg     = (int*)(wsb + alloc(N_NODES * 4));
    float* dis   = (float*)(wsb + alloc(N_NODES * 4));
    int* bsum    = (int*)(wsb + alloc(512 * 4));
    unsigned short* w1T = (unsigned short*)(wsb + alloc((size_t)IN_DIM_ * HID_ * 2));
    unsigned short* w2T = (unsigned short*)(wsb + alloc((size_t)HID_ * OUT_ * 2));
    int* ecsr    = (int*)(wsb + alloc((size_t)N_EDGES * 4));                             // 6.4MB
    unsigned short* xb  = (unsigned short*)(wsb + alloc((size_t)N_NODES * IN_DIM_ * 2)); // 51.2MB
    unsigned short* h1  = (unsigned short*)(wsb + alloc((size_t)N_NODES * HID_ * 2));    // 51.2MB
    unsigned short* g_a = (unsigned short*)(wsb + alloc((size_t)N_NODES * OUT_ * 2));    // 12.8MB
    unsigned short* g_b = h1;  // h1 dead after gemm2

    hipMemsetAsync(cursor, 0, N_NODES * sizeof(int), stream);
    hipMemsetAsync(deg, 0, N_NODES * sizeof(int), stream);
    gamma_kernel<<<1, 64, 0, stream>>>(alpha, gamma);
    deg_kernel<<<(N_EDGES + 255) / 256, 256, 0, stream>>>(row, deg, N_EDGES);
    dis_kernel<<<NBLK, 256, 0, stream>>>(deg, dis, N_NODES);
    scan_sum_kernel<<<NBLK, 256, 0, stream>>>(deg, bsum, N_NODES);
    scan_block_kernel<<<1, 512, 0, stream>>>(bsum, off, NBLK, N_NODES);
    scan_final_kernel<<<NBLK, 256, 0, stream>>>(deg, bsum, off, N_NODES);
    csr_scatter_kernel<<<(N_EDGES + 255) / 256, 256, 0, stream>>>(row, col, off, cursor,
                                                                  ecsr, N_EDGES);
    wcast_kernel<<<dim3(1, HID_), 256, 0, stream>>>(W1, w1T, IN_DIM_, HID_);
    wcast_kernel<<<dim3(1, OUT_), 256, 0, stream>>>(W2, w2T, HID_, OUT_);
    xcast_kernel<<<(N_NODES * IN_DIM_ / 8 + 255) / 256, 256, 0, stream>>>(
        x, xb, N_NODES * IN_DIM_ / 8);

    gemm1_kernel<<<(N_NODES + 127) / 128, 512, 0, stream>>>(xb, w1T, b1, h1, N_NODES);
    gemm2_kernel<<<(N_NODES + 63) / 64, 256, 0, stream>>>(h1, w2T, b2, gamma, dis, g_a, out,
                                                          N_NODES);

    unsigned short* gc = g_a;
    unsigned short* gn = g_b;
    for (int k = 1; k <= KSTEPS; ++k) {
        pull_kernel<<<(N_NODES + 3) / 4, 256, 0, stream>>>(off, ecsr, dis, gc, gn, out, gamma,
                                                           k, N_NODES);
        unsigned short* t = gc; gc = gn; gn = t;
    }
}